// Round 4
// baseline (606.504 us; speedup 1.0000x reference)
//
#include <hip/hip_runtime.h>

// out[h,k,v] = 0.95*M[h,k,v] + sum_{b,s} rho[b,s]*K[b,s,h,k]*V[b,s,h,v]
// B=4, S=4096 (ROWS=16384), H=16, Dk=Dv=64. fp32 (no fp32 MFMA on CDNA4).
//
// R4: ZERO-LDS, ZERO-BARRIER main loop. Each wave owns (head h, 64 rows) and
// keeps the full 64x64 accumulator in registers (8x8 per lane). Lane (tk,tv)
// loads K[r, tk*8..+8) and V[r, tv*8..+8) directly from global: 8 lanes share
// each 32B segment -> one wave-op covers one contiguous 256B row. rho is
// wave-uniform (s_load). Software pipeline depth 1 (prefetch row r+1 during
// row r's 64 FMAs). Epilogue: pad-68 LDS reduce (conflict-free) + coalesced
// device atomics into out (pre-initialized to 0.95*M).

constexpr int HH = 16;
constexpr int DK = 64;
constexpr int DV = 64;
constexpr int ROWS = 16384;
constexpr int NSLICE = 64;            // grid.x
constexpr int RPB = ROWS / NSLICE;    // 256 rows per block
constexpr int RPW = RPB / 4;          // 64 rows per wave
constexpr int RSTRIDE = HH * DK;      // 1024 floats between consecutive rows
constexpr int PAD = 68;               // LDS row stride (floats), breaks mod-32
constexpr float DECAY = 0.95f;

__global__ __launch_bounds__(256) void init_out(const float* __restrict__ mem,
                                                float* __restrict__ out) {
    int i = blockIdx.x * 256 + threadIdx.x;
    out[i] = DECAY * mem[i];
}

__global__ __launch_bounds__(256, 4) void accum(const float* __restrict__ keys,
                                                const float* __restrict__ values,
                                                const float* __restrict__ rho,
                                                float* __restrict__ out) {
    __shared__ float red[2][64 * PAD];   // 2 x 17408 B = 34816 B

    const int t    = threadIdx.x;
    const int w    = t >> 6;
    const int lane = t & 63;
    const int tk   = lane >> 3;   // k-group: out rows tk*8..+7
    const int tv   = lane & 7;    // v-group: out cols tv*8..+7
    const int h    = blockIdx.y;
    const int row0 = blockIdx.x * RPB + w * RPW;

    const float* kp = keys   + ((size_t)row0 * HH + h) * DK + tk * 8;
    const float* vp = values + ((size_t)row0 * HH + h) * DV + tv * 8;
    const float* rp = rho + row0;

    float4 acc[8][2];
    #pragma unroll
    for (int i = 0; i < 8; ++i) {
        acc[i][0] = make_float4(0.f, 0.f, 0.f, 0.f);
        acc[i][1] = make_float4(0.f, 0.f, 0.f, 0.f);
    }

    // prologue: row 0 fragments
    float4 ck0 = *(const float4*)kp;
    float4 ck1 = *(const float4*)(kp + 4);
    float4 cv0 = *(const float4*)vp;
    float4 cv1 = *(const float4*)(vp + 4);
    float  cr  = rp[0];

    #define COMPUTE_ROW()                                                   \
    {                                                                       \
        float k0 = ck0.x * cr, k1 = ck0.y * cr, k2 = ck0.z * cr,            \
              k3 = ck0.w * cr, k4 = ck1.x * cr, k5 = ck1.y * cr,            \
              k6 = ck1.z * cr, k7 = ck1.w * cr;                             \
        _Pragma("unroll")                                                   \
        for (int _d = 0; _d < 1; ++_d) {                                    \
            float kv[8] = {k0, k1, k2, k3, k4, k5, k6, k7};                 \
            _Pragma("unroll")                                               \
            for (int i = 0; i < 8; ++i) {                                   \
                acc[i][0].x = fmaf(kv[i], cv0.x, acc[i][0].x);              \
                acc[i][0].y = fmaf(kv[i], cv0.y, acc[i][0].y);              \
                acc[i][0].z = fmaf(kv[i], cv0.z, acc[i][0].z);              \
                acc[i][0].w = fmaf(kv[i], cv0.w, acc[i][0].w);              \
                acc[i][1].x = fmaf(kv[i], cv1.x, acc[i][1].x);              \
                acc[i][1].y = fmaf(kv[i], cv1.y, acc[i][1].y);              \
                acc[i][1].z = fmaf(kv[i], cv1.z, acc[i][1].z);              \
                acc[i][1].w = fmaf(kv[i], cv1.w, acc[i][1].w);              \
            }                                                               \
        }                                                                   \
    }

    for (int r = 0; r < RPW - 1; ++r) {
        // prefetch row r+1 (issued before the FMA block; covers VMEM latency)
        const float* kq = kp + (size_t)(r + 1) * RSTRIDE;
        const float* vq = vp + (size_t)(r + 1) * RSTRIDE;
        float4 nk0 = *(const float4*)kq;
        float4 nk1 = *(const float4*)(kq + 4);
        float4 nv0 = *(const float4*)vq;
        float4 nv1 = *(const float4*)(vq + 4);
        float  nr  = rp[r + 1];

        COMPUTE_ROW();

        ck0 = nk0; ck1 = nk1; cv0 = nv0; cv1 = nv1; cr = nr;
    }
    COMPUTE_ROW();   // last row
    #undef COMPUTE_ROW

    // ---- epilogue: pairwise-reduce 4 wave partials (pad-68, conflict-free) ----
    float* dst = red[w & 1];
    if (w < 2) {
        #pragma unroll
        for (int i = 0; i < 8; ++i) {
            *(float4*)(dst + (tk * 8 + i) * PAD + tv * 8)     = acc[i][0];
            *(float4*)(dst + (tk * 8 + i) * PAD + tv * 8 + 4) = acc[i][1];
        }
    }
    __syncthreads();
    if (w >= 2) {
        #pragma unroll
        for (int i = 0; i < 8; ++i) {
            float4* p0 = (float4*)(dst + (tk * 8 + i) * PAD + tv * 8);
            float4* p1 = p0 + 1;
            float4 c0 = *p0, c1 = *p1;
            c0.x += acc[i][0].x; c0.y += acc[i][0].y;
            c0.z += acc[i][0].z; c0.w += acc[i][0].w;
            c1.x += acc[i][1].x; c1.y += acc[i][1].y;
            c1.z += acc[i][1].z; c1.w += acc[i][1].w;
            *p0 = c0; *p1 = c1;
        }
    }
    __syncthreads();

    // coalesced atomics: thread t handles out-flat idx i*256+t; per wave-op this
    // reads exactly one padded LDS row (bank-conflict-free) and hits 64
    // consecutive global dwords.
    float* o = out + h * (DK * DV);
    #pragma unroll
    for (int i = 0; i < 16; ++i) {
        int idx = i * 256 + t;
        int rr = idx >> 6, cc = idx & 63;
        atomicAdd(o + idx, red[0][rr * PAD + cc] + red[1][rr * PAD + cc]);
    }
}

extern "C" void kernel_launch(void* const* d_in, const int* in_sizes, int n_in,
                              void* d_out, int out_size, void* d_ws, size_t ws_size,
                              hipStream_t stream) {
    const float* mem    = (const float*)d_in[0];  // (H, Dk, Dv)
    const float* keys   = (const float*)d_in[1];  // (B, S, H, Dk)
    const float* values = (const float*)d_in[2];  // (B, S, H, Dv)
    const float* rho    = (const float*)d_in[3];  // (B, S)
    float* out = (float*)d_out;                   // (H, Dk, Dv)

    init_out<<<dim3((HH * DK * DV) / 256), dim3(256), 0, stream>>>(mem, out);

    dim3 grid(NSLICE, HH);
    accum<<<grid, dim3(256), 0, stream>>>(keys, values, rho, out);
}

// Round 5
// 184.061 us; speedup vs baseline: 3.2951x; 3.2951x over previous
//
#include <hip/hip_runtime.h>

// out[h,k,v] = 0.95*M[h,k,v] + sum_{b,s} rho[b,s]*K[b,s,h,k]*V[b,s,h,v]
// B=4, S=4096 (ROWS=16384), H=16, Dk=Dv=64. fp32 (no fp32 MFMA on CDNA4).
//
// R5 = R4 structure with the register-spill cause removed:
//   - NO __launch_bounds__ min-waves clamp (R2/R4's VGPR=64 + 961MB scratch
//     traffic came from the (256,4) cap; R3 proved ~108 VGPR runs unspilled).
//   - #pragma unroll 1 on the row loop so the compiler can't double the live
//     range by unrolling.
// Main loop: zero LDS, zero barriers. Wave owns (head, 64 rows); lane (tk,tv)
// holds an 8x8 outer-product accumulator (64 VGPR). K/V fragments loaded
// directly from global: 8 lanes share each 32B segment, one wave-op covers one
// contiguous 256B row (broadcast-coalesced). rho is wave-uniform (s_load).
// 1-row lookahead pipeline. Epilogue: LDS pairwise reduce + coalesced atomics
// into out (pre-initialized to 0.95*M by init_out).

constexpr int HH = 16;
constexpr int DK = 64;
constexpr int DV = 64;
constexpr int ROWS = 16384;
constexpr int NSLICE = 64;            // grid.x
constexpr int RPB = ROWS / NSLICE;    // 256 rows per block
constexpr int RPW = RPB / 4;          // 64 rows per wave
constexpr int RSTRIDE = HH * DK;      // 1024 floats between consecutive rows
constexpr int PAD = 68;               // LDS row stride (floats)
constexpr float DECAY = 0.95f;

__global__ __launch_bounds__(256) void init_out(const float* __restrict__ mem,
                                                float* __restrict__ out) {
    int i = blockIdx.x * 256 + threadIdx.x;
    out[i] = DECAY * mem[i];
}

__global__ __launch_bounds__(256) void accum(const float* __restrict__ keys,
                                             const float* __restrict__ values,
                                             const float* __restrict__ rho,
                                             float* __restrict__ out) {
    __shared__ float red[2][64 * PAD];   // epilogue only

    const int t    = threadIdx.x;
    const int w    = t >> 6;
    const int lane = t & 63;
    const int tk   = lane >> 3;   // k-group: out rows tk*8..+7
    const int tv   = lane & 7;    // v-group: out cols tv*8..+7
    const int h    = blockIdx.y;
    const int row0 = blockIdx.x * RPB + w * RPW;

    const float* kp = keys   + ((size_t)row0 * HH + h) * DK + tk * 8;
    const float* vp = values + ((size_t)row0 * HH + h) * DV + tv * 8;
    const float* rp = rho + row0;

    float4 acc[8][2];
    #pragma unroll
    for (int i = 0; i < 8; ++i) {
        acc[i][0] = make_float4(0.f, 0.f, 0.f, 0.f);
        acc[i][1] = make_float4(0.f, 0.f, 0.f, 0.f);
    }

    // current-row fragments (row 0)
    float4 ck0 = *(const float4*)kp;
    float4 ck1 = *(const float4*)(kp + 4);
    float4 cv0 = *(const float4*)vp;
    float4 cv1 = *(const float4*)(vp + 4);
    float  cr  = rp[0];

    #define COMPUTE_ROW()                                                   \
    {                                                                       \
        float k0 = ck0.x * cr, k1 = ck0.y * cr, k2 = ck0.z * cr,            \
              k3 = ck0.w * cr, k4 = ck1.x * cr, k5 = ck1.y * cr,            \
              k6 = ck1.z * cr, k7 = ck1.w * cr;                             \
        acc[0][0].x = fmaf(k0, cv0.x, acc[0][0].x);                         \
        acc[0][0].y = fmaf(k0, cv0.y, acc[0][0].y);                         \
        acc[0][0].z = fmaf(k0, cv0.z, acc[0][0].z);                         \
        acc[0][0].w = fmaf(k0, cv0.w, acc[0][0].w);                         \
        acc[0][1].x = fmaf(k0, cv1.x, acc[0][1].x);                         \
        acc[0][1].y = fmaf(k0, cv1.y, acc[0][1].y);                         \
        acc[0][1].z = fmaf(k0, cv1.z, acc[0][1].z);                         \
        acc[0][1].w = fmaf(k0, cv1.w, acc[0][1].w);                         \
        acc[1][0].x = fmaf(k1, cv0.x, acc[1][0].x);                         \
        acc[1][0].y = fmaf(k1, cv0.y, acc[1][0].y);                         \
        acc[1][0].z = fmaf(k1, cv0.z, acc[1][0].z);                         \
        acc[1][0].w = fmaf(k1, cv0.w, acc[1][0].w);                         \
        acc[1][1].x = fmaf(k1, cv1.x, acc[1][1].x);                         \
        acc[1][1].y = fmaf(k1, cv1.y, acc[1][1].y);                         \
        acc[1][1].z = fmaf(k1, cv1.z, acc[1][1].z);                         \
        acc[1][1].w = fmaf(k1, cv1.w, acc[1][1].w);                         \
        acc[2][0].x = fmaf(k2, cv0.x, acc[2][0].x);                         \
        acc[2][0].y = fmaf(k2, cv0.y, acc[2][0].y);                         \
        acc[2][0].z = fmaf(k2, cv0.z, acc[2][0].z);                         \
        acc[2][0].w = fmaf(k2, cv0.w, acc[2][0].w);                         \
        acc[2][1].x = fmaf(k2, cv1.x, acc[2][1].x);                         \
        acc[2][1].y = fmaf(k2, cv1.y, acc[2][1].y);                         \
        acc[2][1].z = fmaf(k2, cv1.z, acc[2][1].z);                         \
        acc[2][1].w = fmaf(k2, cv1.w, acc[2][1].w);                         \
        acc[3][0].x = fmaf(k3, cv0.x, acc[3][0].x);                         \
        acc[3][0].y = fmaf(k3, cv0.y, acc[3][0].y);                         \
        acc[3][0].z = fmaf(k3, cv0.z, acc[3][0].z);                         \
        acc[3][0].w = fmaf(k3, cv0.w, acc[3][0].w);                         \
        acc[3][1].x = fmaf(k3, cv1.x, acc[3][1].x);                         \
        acc[3][1].y = fmaf(k3, cv1.y, acc[3][1].y);                         \
        acc[3][1].z = fmaf(k3, cv1.z, acc[3][1].z);                         \
        acc[3][1].w = fmaf(k3, cv1.w, acc[3][1].w);                         \
        acc[4][0].x = fmaf(k4, cv0.x, acc[4][0].x);                         \
        acc[4][0].y = fmaf(k4, cv0.y, acc[4][0].y);                         \
        acc[4][0].z = fmaf(k4, cv0.z, acc[4][0].z);                         \
        acc[4][0].w = fmaf(k4, cv0.w, acc[4][0].w);                         \
        acc[4][1].x = fmaf(k4, cv1.x, acc[4][1].x);                         \
        acc[4][1].y = fmaf(k4, cv1.y, acc[4][1].y);                         \
        acc[4][1].z = fmaf(k4, cv1.z, acc[4][1].z);                         \
        acc[4][1].w = fmaf(k4, cv1.w, acc[4][1].w);                         \
        acc[5][0].x = fmaf(k5, cv0.x, acc[5][0].x);                         \
        acc[5][0].y = fmaf(k5, cv0.y, acc[5][0].y);                         \
        acc[5][0].z = fmaf(k5, cv0.z, acc[5][0].z);                         \
        acc[5][0].w = fmaf(k5, cv0.w, acc[5][0].w);                         \
        acc[5][1].x = fmaf(k5, cv1.x, acc[5][1].x);                         \
        acc[5][1].y = fmaf(k5, cv1.y, acc[5][1].y);                         \
        acc[5][1].z = fmaf(k5, cv1.z, acc[5][1].z);                         \
        acc[5][1].w = fmaf(k5, cv1.w, acc[5][1].w);                         \
        acc[6][0].x = fmaf(k6, cv0.x, acc[6][0].x);                         \
        acc[6][0].y = fmaf(k6, cv0.y, acc[6][0].y);                         \
        acc[6][0].z = fmaf(k6, cv0.z, acc[6][0].z);                         \
        acc[6][0].w = fmaf(k6, cv0.w, acc[6][0].w);                         \
        acc[6][1].x = fmaf(k6, cv1.x, acc[6][1].x);                         \
        acc[6][1].y = fmaf(k6, cv1.y, acc[6][1].y);                         \
        acc[6][1].z = fmaf(k6, cv1.z, acc[6][1].z);                         \
        acc[6][1].w = fmaf(k6, cv1.w, acc[6][1].w);                         \
        acc[7][0].x = fmaf(k7, cv0.x, acc[7][0].x);                         \
        acc[7][0].y = fmaf(k7, cv0.y, acc[7][0].y);                         \
        acc[7][0].z = fmaf(k7, cv0.z, acc[7][0].z);                         \
        acc[7][0].w = fmaf(k7, cv0.w, acc[7][0].w);                         \
        acc[7][1].x = fmaf(k7, cv1.x, acc[7][1].x);                         \
        acc[7][1].y = fmaf(k7, cv1.y, acc[7][1].y);                         \
        acc[7][1].z = fmaf(k7, cv1.z, acc[7][1].z);                         \
        acc[7][1].w = fmaf(k7, cv1.w, acc[7][1].w);                         \
    }

    #pragma unroll 1
    for (int r = 0; r < RPW - 1; ++r) {
        const float* kq = kp + (size_t)(r + 1) * RSTRIDE;
        const float* vq = vp + (size_t)(r + 1) * RSTRIDE;
        float4 nk0 = *(const float4*)kq;
        float4 nk1 = *(const float4*)(kq + 4);
        float4 nv0 = *(const float4*)vq;
        float4 nv1 = *(const float4*)(vq + 4);
        float  nr  = rp[r + 1];

        COMPUTE_ROW();

        ck0 = nk0; ck1 = nk1; cv0 = nv0; cv1 = nv1; cr = nr;
    }
    COMPUTE_ROW();   // last row
    #undef COMPUTE_ROW

    // ---- epilogue: pairwise-reduce 4 wave partials, then coalesced atomics ----
    float* dst = red[w & 1];
    if (w < 2) {
        #pragma unroll
        for (int i = 0; i < 8; ++i) {
            *(float4*)(dst + (tk * 8 + i) * PAD + tv * 8)     = acc[i][0];
            *(float4*)(dst + (tk * 8 + i) * PAD + tv * 8 + 4) = acc[i][1];
        }
    }
    __syncthreads();
    if (w >= 2) {
        #pragma unroll
        for (int i = 0; i < 8; ++i) {
            float4* p0 = (float4*)(dst + (tk * 8 + i) * PAD + tv * 8);
            float4* p1 = p0 + 1;
            float4 c0 = *p0, c1 = *p1;
            c0.x += acc[i][0].x; c0.y += acc[i][0].y;
            c0.z += acc[i][0].z; c0.w += acc[i][0].w;
            c1.x += acc[i][1].x; c1.y += acc[i][1].y;
            c1.z += acc[i][1].z; c1.w += acc[i][1].w;
            *p0 = c0; *p1 = c1;
        }
    }
    __syncthreads();

    float* o = out + h * (DK * DV);
    #pragma unroll
    for (int i = 0; i < 16; ++i) {
        int idx = i * 256 + t;
        int rr = idx >> 6, cc = idx & 63;
        atomicAdd(o + idx, red[0][rr * PAD + cc] + red[1][rr * PAD + cc]);
    }
}

extern "C" void kernel_launch(void* const* d_in, const int* in_sizes, int n_in,
                              void* d_out, int out_size, void* d_ws, size_t ws_size,
                              hipStream_t stream) {
    const float* mem    = (const float*)d_in[0];  // (H, Dk, Dv)
    const float* keys   = (const float*)d_in[1];  // (B, S, H, Dk)
    const float* values = (const float*)d_in[2];  // (B, S, H, Dv)
    const float* rho    = (const float*)d_in[3];  // (B, S)
    float* out = (float*)d_out;                   // (H, Dk, Dv)

    init_out<<<dim3((HH * DK * DV) / 256), dim3(256), 0, stream>>>(mem, out);

    dim3 grid(NSLICE, HH);
    accum<<<grid, dim3(256), 0, stream>>>(keys, values, rho, out);
}

// Round 6
// 161.641 us; speedup vs baseline: 3.7522x; 1.1387x over previous
//
#include <hip/hip_runtime.h>

// out[h,k,v] = 0.95*M[h,k,v] + sum_{b,s} rho[b,s]*K[b,s,h,k]*V[b,s,h,v]
// B=4, S=4096 (ROWS=16384), H=16, Dk=Dv=64.
//
// R6: bf16 MFMA path. The fp32-VALU path has a 15.4 us issue floor and binds
// on latency (R1/R3/R5: 57/65/74 us, VALUBusy ~30%). MFMA collapses compute to
// ~1.5 us total, leaving a memory-shaped kernel.
//   - main loop: ZERO LDS, ZERO barriers. Wave owns (head, 64 s-rows), 2 tiles
//     of 32 rows; per tile it loads MFMA fragments DIRECTLY from global
//     (per-lane dword column-walks; each wave-op = 4 x 64B segments).
//   - A-frag[mt]: lane(m=lane&15,q=lane>>4) holds rho[s]*K[s][mt*16+m] for
//     s = s0+q*8+j (j=0..7)  [layout verified learn_hip m120]
//   - B-frag[nt]: same with V, n=lane&15 [symmetric]
//   - acc: 4x4 tiles of floatx4, C/D: col=lane&15, row=q*4+reg [m89/m91]
//   - epilogue: pairwise LDS reduce (pad 65, conflict-light) + coalesced
//     atomics into out (pre-initialized to 0.95*M).
// Numerics: bf16 rounding on (rho*k) and v, fp32 accumulation; est absmax
// ~1.5-2 vs threshold 6.04.

typedef __bf16  bf16x8  __attribute__((ext_vector_type(8)));
typedef float   floatx4 __attribute__((ext_vector_type(4)));

constexpr int HH = 16;
constexpr int DK = 64;
constexpr int DV = 64;
constexpr int ROWS = 16384;
constexpr int NSLICE = 64;            // grid.x
constexpr int RPB = ROWS / NSLICE;    // 256 rows per block
constexpr int RPW = RPB / 4;          // 64 rows per wave
constexpr int TS  = 32;               // s-rows per MFMA step (K-dim)
constexpr int NT  = RPW / TS;         // 2 tiles per wave
constexpr int PAD = 65;               // LDS row stride (floats)
constexpr float DECAY = 0.95f;

__global__ __launch_bounds__(256) void init_out(const float* __restrict__ mem,
                                                float* __restrict__ out) {
    int i = blockIdx.x * 256 + threadIdx.x;
    out[i] = DECAY * mem[i];
}

__global__ __launch_bounds__(256) void accum(const float* __restrict__ keys,
                                             const float* __restrict__ values,
                                             const float* __restrict__ rho,
                                             float* __restrict__ out) {
    __shared__ float red[2][64 * PAD];   // 33,280 B, epilogue only

    const int t    = threadIdx.x;
    const int w    = t >> 6;
    const int lane = t & 63;
    const int m15  = lane & 15;
    const int q    = lane >> 4;
    const int h    = blockIdx.y;
    const int row0 = blockIdx.x * RPB + w * RPW;

    floatx4 acc[4][4];
    #pragma unroll
    for (int i = 0; i < 4; ++i)
        #pragma unroll
        for (int j = 0; j < 4; ++j)
            acc[i][j] = (floatx4){0.f, 0.f, 0.f, 0.f};

    #pragma unroll
    for (int tile = 0; tile < NT; ++tile) {
        const int s0 = row0 + tile * TS;
        const int sl = s0 + q * 8;            // this lane's first s

        // rho[sl..sl+8) — 16 lanes share each address (L1 broadcast)
        float4 r0 = *(const float4*)(rho + sl);
        float4 r1 = *(const float4*)(rho + sl + 4);
        float rv[8] = {r0.x, r0.y, r0.z, r0.w, r1.x, r1.y, r1.z, r1.w};

        // element (s, col): keys[((s*HH)+h)*DK + col]; j step = HH*DK floats
        const float* kbase = keys   + ((size_t)sl * HH + h) * DK + m15;
        const float* vbase = values + ((size_t)sl * HH + h) * DV + m15;

        bf16x8 af[4], bfr[4];
        #pragma unroll
        for (int mt = 0; mt < 4; ++mt) {
            #pragma unroll
            for (int j = 0; j < 8; ++j) {
                float x = kbase[(size_t)j * (HH * DK) + mt * 16] * rv[j];
                af[mt][j] = (__bf16)x;
            }
        }
        #pragma unroll
        for (int nt = 0; nt < 4; ++nt) {
            #pragma unroll
            for (int j = 0; j < 8; ++j) {
                float x = vbase[(size_t)j * (HH * DV) + nt * 16];
                bfr[nt][j] = (__bf16)x;
            }
        }

        #pragma unroll
        for (int mt = 0; mt < 4; ++mt)
            #pragma unroll
            for (int nt = 0; nt < 4; ++nt)
                acc[mt][nt] = __builtin_amdgcn_mfma_f32_16x16x32_bf16(
                    af[mt], bfr[nt], acc[mt][nt], 0, 0, 0);
    }

    // ---- epilogue: pairwise-reduce 4 wave partials in LDS, then atomics ----
    // C/D mapping: element [row = mt*16 + q*4 + r][col = nt*16 + m15]
    float* dst = red[w & 1];
    if (w < 2) {
        #pragma unroll
        for (int mt = 0; mt < 4; ++mt)
            #pragma unroll
            for (int nt = 0; nt < 4; ++nt)
                #pragma unroll
                for (int r = 0; r < 4; ++r)
                    dst[(mt * 16 + q * 4 + r) * PAD + nt * 16 + m15] = acc[mt][nt][r];
    }
    __syncthreads();
    if (w >= 2) {
        #pragma unroll
        for (int mt = 0; mt < 4; ++mt)
            #pragma unroll
            for (int nt = 0; nt < 4; ++nt)
                #pragma unroll
                for (int r = 0; r < 4; ++r) {
                    float* p = &dst[(mt * 16 + q * 4 + r) * PAD + nt * 16 + m15];
                    *p = *p + acc[mt][nt][r];
                }
    }
    __syncthreads();

    float* o = out + h * (DK * DV);
    #pragma unroll
    for (int i = 0; i < 16; ++i) {
        int idx = i * 256 + t;
        int rr = idx >> 6, cc = idx & 63;
        atomicAdd(o + idx, red[0][rr * PAD + cc] + red[1][rr * PAD + cc]);
    }
}

extern "C" void kernel_launch(void* const* d_in, const int* in_sizes, int n_in,
                              void* d_out, int out_size, void* d_ws, size_t ws_size,
                              hipStream_t stream) {
    const float* mem    = (const float*)d_in[0];  // (H, Dk, Dv)
    const float* keys   = (const float*)d_in[1];  // (B, S, H, Dk)
    const float* values = (const float*)d_in[2];  // (B, S, H, Dv)
    const float* rho    = (const float*)d_in[3];  // (B, S)
    float* out = (float*)d_out;                   // (H, Dk, Dv)

    init_out<<<dim3((HH * DK * DV) / 256), dim3(256), 0, stream>>>(mem, out);

    dim3 grid(NSLICE, HH);
    accum<<<grid, dim3(256), 0, stream>>>(keys, values, rho, out);
}